// Round 14
// baseline (122.878 us; speedup 1.0000x reference)
//
#include <hip/hip_runtime.h>
#include <math.h>

// SinkhornWarpInterpolator, v4: 1 window/block, no-spill Sinkhorn.
// 1024 blocks x 256 threads, LDS 37.9KB -> 4 blocks/CU (launch_bounds(256,4)).
// Layouts from v2 (proven conflict-free): f0 token-major, f1t d-major.
// GEMM epilogue writes E = exp(logits) to LDS (reuses f0).
// Owner wave (blk&3): K rows in 64 VGPRs (no KT -> no spill);
//   R-update u=1/(K.v) from regs, C-update v_l = 1/sum_i E[i][l]*u_i
//   reads E rows from LDS (64 consecutive floats = conflict-free).

#define S0 68   // LDS row stride in floats (16B aligned, bank-spreading)

__device__ __forceinline__ float rlane(float v, int l) {
    return __uint_as_float(__builtin_amdgcn_readlane(__float_as_uint(v), l));
}

__global__ __launch_bounds__(256, 4)
void skw_kernel(const float* __restrict__ z0, const float* __restrict__ z1,
                float* __restrict__ out) {
    __shared__ float f0 [64 * S0];        // z0 tokens; becomes E after GEMM
    __shared__ float f1t[64 * S0];        // z1 features, d-major (transposed)
    __shared__ float psq0[256], psq1[256];
    __shared__ float invn0[64], invn1[64];
    __shared__ float dispx[64], dispy[64];

    const int t   = threadIdx.x;
    const int blk = blockIdx.x;            // 1024 = b(16) x wy(8) x wx(8)
    const int b   = blk >> 6;
    const int wy  = (blk >> 3) & 7;
    const int wx  = blk & 7;
    const int Y0  = wy * 32, X0 = wx * 32;

    const int xq = t & 7;                  // float4 column within 32 px
    const int yy = (t >> 3) & 31;          // pixel row within window
    const int mm = (yy >> 2) * 8 + xq;     // token index
    const int pi = yy & 3;                 // row within patch

    // ---- stage: z0 -> f0 (token-major), z1 -> f1t (d-major) + sumsq ----
    {
        const size_t base = (size_t)(b * 4) * 65536 + (size_t)(Y0 + yy) * 256 + X0 + xq * 4;
        const float* s0p = z0 + base;
        const float* s1p = z1 + base;
        float a0 = 0.f;
        #pragma unroll
        for (int c = 0; c < 4; ++c) {
            float4 vv = *(const float4*)(s0p + c * 65536);
            a0 += vv.x*vv.x + vv.y*vv.y + vv.z*vv.z + vv.w*vv.w;
            *(float4*)&f0[mm * S0 + c * 16 + pi * 4] = vv;
        }
        psq0[t] = a0;
        float a1 = 0.f;
        #pragma unroll
        for (int c = 0; c < 4; ++c) {
            float4 vv = *(const float4*)(s1p + c * 65536);
            a1 += vv.x*vv.x + vv.y*vv.y + vv.z*vv.z + vv.w*vv.w;
            const int d = c * 16 + pi * 4;
            f1t[(d+0)*S0 + mm] = vv.x;
            f1t[(d+1)*S0 + mm] = vv.y;
            f1t[(d+2)*S0 + mm] = vv.z;
            f1t[(d+3)*S0 + mm] = vv.w;
        }
        psq1[t] = a1;
    }
    __syncthreads();
    if (t < 128) {
        const int u2 = t & 63;
        const float* ps = (t < 64) ? psq0 : psq1;
        const int ti = u2 >> 3, tj = u2 & 7;
        float s = ps[(ti*4+0)*8+tj] + ps[(ti*4+1)*8+tj]
                + ps[(ti*4+2)*8+tj] + ps[(ti*4+3)*8+tj];
        float r = 1.0f / fmaxf(sqrtf(s), 1e-6f);
        if (t < 64) invn0[u2] = r; else invn1[u2] = r;
    }
    __syncthreads();

    // ---- GEMM (v2 pattern, conflict-free): 4x4 block per thread ----
    const int bi = t >> 4, bj = t & 15;
    float acc[4][4];
    #pragma unroll
    for (int r = 0; r < 4; ++r)
        #pragma unroll
        for (int s2 = 0; s2 < 4; ++s2) acc[r][s2] = 0.f;

    #pragma unroll 4
    for (int dc = 0; dc < 16; ++dc) {
        float4 A[4], Bv[4];
        #pragma unroll
        for (int r = 0; r < 4; ++r) A[r] = *(const float4*)&f0[(bi*4+r)*S0 + dc*4];
        #pragma unroll
        for (int dd = 0; dd < 4; ++dd) Bv[dd] = *(const float4*)&f1t[(dc*4+dd)*S0 + bj*4];
        #pragma unroll
        for (int r = 0; r < 4; ++r) {
            acc[r][0] += A[r].x*Bv[0].x + A[r].y*Bv[1].x + A[r].z*Bv[2].x + A[r].w*Bv[3].x;
            acc[r][1] += A[r].x*Bv[0].y + A[r].y*Bv[1].y + A[r].z*Bv[2].y + A[r].w*Bv[3].y;
            acc[r][2] += A[r].x*Bv[0].z + A[r].y*Bv[1].z + A[r].z*Bv[2].z + A[r].w*Bv[3].z;
            acc[r][3] += A[r].x*Bv[0].w + A[r].y*Bv[1].w + A[r].z*Bv[2].w + A[r].w*Bv[3].w;
        }
    }
    float si[4], sj[4];
    #pragma unroll
    for (int r = 0; r < 4; ++r)  si[r] = invn0[bi*4+r] * 20.0f;   // 1/TAU
    #pragma unroll
    for (int s2 = 0; s2 < 4; ++s2) sj[s2] = invn1[bj*4+s2];
    __syncthreads();               // everyone done reading f0/f1t
    float* Mm = f0;                // reuse f0 as E = exp(scaled logits)
    #pragma unroll
    for (int r = 0; r < 4; ++r) {
        float4 o;
        o.x = __expf(acc[r][0]*si[r]*sj[0]);
        o.y = __expf(acc[r][1]*si[r]*sj[1]);
        o.z = __expf(acc[r][2]*si[r]*sj[2]);
        o.w = __expf(acc[r][3]*si[r]*sj[3]);
        *(float4*)&Mm[(bi*4+r)*S0 + bj*4] = o;
    }
    __syncthreads();

    // ---- owner wave: K rows in regs, E columns from LDS; no KT, no spill ----
    const int lane = t & 63;
    if ((t >> 6) == (blk & 3)) {           // spread owner waves across SIMDs
        float K[64];
        #pragma unroll
        for (int j4 = 0; j4 < 16; ++j4) {
            float4 r4 = *(const float4*)&Mm[lane * S0 + j4 * 4];
            K[4*j4+0] = r4.x; K[4*j4+1] = r4.y;
            K[4*j4+2] = r4.z; K[4*j4+3] = r4.w;
        }
        float u, v;
        {
            float s0=0.f, s1=0.f, s2=0.f, s3=0.f;        // R-update #1 (v==1)
            #pragma unroll
            for (int j = 0; j < 64; j += 4) {
                s0 += K[j]; s1 += K[j+1]; s2 += K[j+2]; s3 += K[j+3];
            }
            u = 1.0f / ((s0+s1) + (s2+s3));
        }
        #pragma unroll 1
        for (int it = 0; it < 19; ++it) {
            float s0=0.f, s1=0.f, s2=0.f, s3=0.f;        // C-update: E cols from LDS
            #pragma unroll
            for (int i = 0; i < 64; i += 4) {
                s0 = fmaf(Mm[(i+0)*S0 + lane], rlane(u, i+0), s0);
                s1 = fmaf(Mm[(i+1)*S0 + lane], rlane(u, i+1), s1);
                s2 = fmaf(Mm[(i+2)*S0 + lane], rlane(u, i+2), s2);
                s3 = fmaf(Mm[(i+3)*S0 + lane], rlane(u, i+3), s3);
            }
            v = 1.0f / ((s0+s1) + (s2+s3));
            s0=0.f; s1=0.f; s2=0.f; s3=0.f;              // R-update: K regs
            #pragma unroll
            for (int j = 0; j < 64; j += 4) {
                s0 = fmaf(K[j  ], rlane(v, j  ), s0);
                s1 = fmaf(K[j+1], rlane(v, j+1), s1);
                s2 = fmaf(K[j+2], rlane(v, j+2), s2);
                s3 = fmaf(K[j+3], rlane(v, j+3), s3);
            }
            u = 1.0f / ((s0+s1) + (s2+s3));
        }
        {
            float s0=0.f, s1=0.f, s2=0.f, s3=0.f;        // C-update #20
            #pragma unroll
            for (int i = 0; i < 64; i += 4) {
                s0 = fmaf(Mm[(i+0)*S0 + lane], rlane(u, i+0), s0);
                s1 = fmaf(Mm[(i+1)*S0 + lane], rlane(u, i+1), s1);
                s2 = fmaf(Mm[(i+2)*S0 + lane], rlane(u, i+2), s2);
                s3 = fmaf(Mm[(i+3)*S0 + lane], rlane(u, i+3), s3);
            }
            v = 1.0f / ((s0+s1) + (s2+s3));
        }
        // final row softmax + expected position (u cancels)
        {
            float ss=0.f, sx=0.f, sy=0.f;
            #pragma unroll
            for (int j = 0; j < 64; ++j) {
                float pj = K[j] * rlane(v, j);
                ss += pj;
                sx = fmaf(pj, (float)(j & 7),  sx);
                sy = fmaf(pj, (float)(j >> 3), sy);
            }
            const float inv = 1.0f / ss;
            dispx[lane] = sx * inv - (float)(lane & 7);
            dispy[lane] = sy * inv - (float)(lane >> 3);
        }
    }
    __syncthreads();

    // ---- warp: bilinear border sample of z1 at (pos + 4*disp) ----
    #pragma unroll
    for (int rep = 0; rep < 4; ++rep) {
        const int p = rep * 256 + t;
        const int y = p >> 5, x = p & 31;
        const int m2 = (y >> 2) * 8 + (x >> 2);
        float gx = (float)(X0 + x) + 4.0f * dispx[m2];
        float gy = (float)(Y0 + y) + 4.0f * dispy[m2];
        gx = fminf(fmaxf(gx, 0.0f), 255.0f);
        gy = fminf(fmaxf(gy, 0.0f), 255.0f);
        const float x0f = floorf(gx), y0f = floorf(gy);
        const float wxf = gx - x0f, wyf = gy - y0f;
        const int xi0 = (int)x0f, yi0 = (int)y0f;
        const int xi1 = min(xi0 + 1, 255), yi1 = min(yi0 + 1, 255);
        const float w00 = (1.f-wxf)*(1.f-wyf), w01 = wxf*(1.f-wyf);
        const float w10 = (1.f-wxf)*wyf,       w11 = wxf*wyf;
        const float* basep = z1 + (size_t)(b * 4) * 65536;
        #pragma unroll
        for (int c = 0; c < 4; ++c) {
            const float* pc = basep + c * 65536;
            const float v00 = pc[yi0*256 + xi0], v01 = pc[yi0*256 + xi1];
            const float v10 = pc[yi1*256 + xi0], v11 = pc[yi1*256 + xi1];
            out[((size_t)(b*4+c)*256 + (Y0+y))*256 + X0 + x]
                = v00*w00 + v01*w01 + v10*w10 + v11*w11;
        }
    }
}

extern "C" void kernel_launch(void* const* d_in, const int* in_sizes, int n_in,
                              void* d_out, int out_size, void* d_ws, size_t ws_size,
                              hipStream_t stream) {
    (void)in_sizes; (void)n_in; (void)d_ws; (void)ws_size; (void)out_size;
    const float* z0 = (const float*)d_in[0];
    const float* z1 = (const float*)d_in[1];
    float* out = (float*)d_out;
    skw_kernel<<<dim3(1024), dim3(256), 0, stream>>>(z0, z1, out);
}

// Round 15
// 122.547 us; speedup vs baseline: 1.0027x; 1.0027x over previous
//
#include <hip/hip_runtime.h>
#include <math.h>

// SinkhornWarpInterpolator, v5: v4 structure, launch_bounds(256,1).
// Lesson (v2=132/v3=84 spill/v4=64 spill): hipcc scratches big per-thread
// arrays under a waves-per-EU cap; (256,1) keeps K[64] in VGPRs. LDS 37.9KB
// is then the occupancy bound -> 4 blocks/CU.
// 1024 blocks x 256 threads; f0 token-major, f1t d-major (conflict-free);
// GEMM epilogue writes E=exp(logits) into f0; owner wave (blk&3) runs
// factored Sinkhorn: R-update from K regs, C-update from E columns in LDS.

#define S0 68   // LDS row stride in floats (16B aligned, bank-spreading)

__device__ __forceinline__ float rlane(float v, int l) {
    return __uint_as_float(__builtin_amdgcn_readlane(__float_as_uint(v), l));
}

__global__ __launch_bounds__(256, 1)
void skw_kernel(const float* __restrict__ z0, const float* __restrict__ z1,
                float* __restrict__ out) {
    __shared__ float f0 [64 * S0];        // z0 tokens; becomes E after GEMM
    __shared__ float f1t[64 * S0];        // z1 features, d-major (transposed)
    __shared__ float psq0[256], psq1[256];
    __shared__ float invn0[64], invn1[64];
    __shared__ float dispx[64], dispy[64];

    const int t   = threadIdx.x;
    const int blk = blockIdx.x;            // 1024 = b(16) x wy(8) x wx(8)
    const int b   = blk >> 6;
    const int wy  = (blk >> 3) & 7;
    const int wx  = blk & 7;
    const int Y0  = wy * 32, X0 = wx * 32;

    const int xq = t & 7;                  // float4 column within 32 px
    const int yy = (t >> 3) & 31;          // pixel row within window
    const int mm = (yy >> 2) * 8 + xq;     // token index
    const int pi = yy & 3;                 // row within patch

    // ---- stage: z0 -> f0 (token-major), z1 -> f1t (d-major) + sumsq ----
    {
        const size_t base = (size_t)(b * 4) * 65536 + (size_t)(Y0 + yy) * 256 + X0 + xq * 4;
        const float* s0p = z0 + base;
        const float* s1p = z1 + base;
        float a0 = 0.f;
        #pragma unroll
        for (int c = 0; c < 4; ++c) {
            float4 vv = *(const float4*)(s0p + c * 65536);
            a0 += vv.x*vv.x + vv.y*vv.y + vv.z*vv.z + vv.w*vv.w;
            *(float4*)&f0[mm * S0 + c * 16 + pi * 4] = vv;
        }
        psq0[t] = a0;
        float a1 = 0.f;
        #pragma unroll
        for (int c = 0; c < 4; ++c) {
            float4 vv = *(const float4*)(s1p + c * 65536);
            a1 += vv.x*vv.x + vv.y*vv.y + vv.z*vv.z + vv.w*vv.w;
            const int d = c * 16 + pi * 4;
            f1t[(d+0)*S0 + mm] = vv.x;
            f1t[(d+1)*S0 + mm] = vv.y;
            f1t[(d+2)*S0 + mm] = vv.z;
            f1t[(d+3)*S0 + mm] = vv.w;
        }
        psq1[t] = a1;
    }
    __syncthreads();
    if (t < 128) {
        const int u2 = t & 63;
        const float* ps = (t < 64) ? psq0 : psq1;
        const int ti = u2 >> 3, tj = u2 & 7;
        float s = ps[(ti*4+0)*8+tj] + ps[(ti*4+1)*8+tj]
                + ps[(ti*4+2)*8+tj] + ps[(ti*4+3)*8+tj];
        float r = 1.0f / fmaxf(sqrtf(s), 1e-6f);
        if (t < 64) invn0[u2] = r; else invn1[u2] = r;
    }
    __syncthreads();

    // ---- GEMM (conflict-free): 4x4 block per thread ----
    const int bi = t >> 4, bj = t & 15;
    float acc[4][4];
    #pragma unroll
    for (int r = 0; r < 4; ++r)
        #pragma unroll
        for (int s2 = 0; s2 < 4; ++s2) acc[r][s2] = 0.f;

    #pragma unroll 4
    for (int dc = 0; dc < 16; ++dc) {
        float4 A[4], Bv[4];
        #pragma unroll
        for (int r = 0; r < 4; ++r) A[r] = *(const float4*)&f0[(bi*4+r)*S0 + dc*4];
        #pragma unroll
        for (int dd = 0; dd < 4; ++dd) Bv[dd] = *(const float4*)&f1t[(dc*4+dd)*S0 + bj*4];
        #pragma unroll
        for (int r = 0; r < 4; ++r) {
            acc[r][0] += A[r].x*Bv[0].x + A[r].y*Bv[1].x + A[r].z*Bv[2].x + A[r].w*Bv[3].x;
            acc[r][1] += A[r].x*Bv[0].y + A[r].y*Bv[1].y + A[r].z*Bv[2].y + A[r].w*Bv[3].y;
            acc[r][2] += A[r].x*Bv[0].z + A[r].y*Bv[1].z + A[r].z*Bv[2].z + A[r].w*Bv[3].z;
            acc[r][3] += A[r].x*Bv[0].w + A[r].y*Bv[1].w + A[r].z*Bv[2].w + A[r].w*Bv[3].w;
        }
    }
    float si[4], sj[4];
    #pragma unroll
    for (int r = 0; r < 4; ++r)  si[r] = invn0[bi*4+r] * 20.0f;   // 1/TAU
    #pragma unroll
    for (int s2 = 0; s2 < 4; ++s2) sj[s2] = invn1[bj*4+s2];
    __syncthreads();               // everyone done reading f0/f1t
    float* Mm = f0;                // reuse f0 as E = exp(scaled logits)
    #pragma unroll
    for (int r = 0; r < 4; ++r) {
        float4 o;
        o.x = __expf(acc[r][0]*si[r]*sj[0]);
        o.y = __expf(acc[r][1]*si[r]*sj[1]);
        o.z = __expf(acc[r][2]*si[r]*sj[2]);
        o.w = __expf(acc[r][3]*si[r]*sj[3]);
        *(float4*)&Mm[(bi*4+r)*S0 + bj*4] = o;
    }
    __syncthreads();

    // ---- owner wave: K rows in regs, E columns from LDS ----
    const int lane = t & 63;
    if ((t >> 6) == (blk & 3)) {           // spread owner waves across SIMDs
        float K[64];
        #pragma unroll
        for (int j4 = 0; j4 < 16; ++j4) {
            float4 r4 = *(const float4*)&Mm[lane * S0 + j4 * 4];
            K[4*j4+0] = r4.x; K[4*j4+1] = r4.y;
            K[4*j4+2] = r4.z; K[4*j4+3] = r4.w;
        }
        float u, v;
        {
            float s0=0.f, s1=0.f, s2=0.f, s3=0.f;        // R-update #1 (v==1)
            #pragma unroll
            for (int j = 0; j < 64; j += 4) {
                s0 += K[j]; s1 += K[j+1]; s2 += K[j+2]; s3 += K[j+3];
            }
            u = 1.0f / ((s0+s1) + (s2+s3));
        }
        #pragma unroll 1
        for (int it = 0; it < 19; ++it) {
            float s0=0.f, s1=0.f, s2=0.f, s3=0.f;        // C-update: E cols from LDS
            #pragma unroll
            for (int i = 0; i < 64; i += 4) {
                s0 = fmaf(Mm[(i+0)*S0 + lane], rlane(u, i+0), s0);
                s1 = fmaf(Mm[(i+1)*S0 + lane], rlane(u, i+1), s1);
                s2 = fmaf(Mm[(i+2)*S0 + lane], rlane(u, i+2), s2);
                s3 = fmaf(Mm[(i+3)*S0 + lane], rlane(u, i+3), s3);
            }
            v = 1.0f / ((s0+s1) + (s2+s3));
            s0=0.f; s1=0.f; s2=0.f; s3=0.f;              // R-update: K regs
            #pragma unroll
            for (int j = 0; j < 64; j += 4) {
                s0 = fmaf(K[j  ], rlane(v, j  ), s0);
                s1 = fmaf(K[j+1], rlane(v, j+1), s1);
                s2 = fmaf(K[j+2], rlane(v, j+2), s2);
                s3 = fmaf(K[j+3], rlane(v, j+3), s3);
            }
            u = 1.0f / ((s0+s1) + (s2+s3));
        }
        {
            float s0=0.f, s1=0.f, s2=0.f, s3=0.f;        // C-update #20
            #pragma unroll
            for (int i = 0; i < 64; i += 4) {
                s0 = fmaf(Mm[(i+0)*S0 + lane], rlane(u, i+0), s0);
                s1 = fmaf(Mm[(i+1)*S0 + lane], rlane(u, i+1), s1);
                s2 = fmaf(Mm[(i+2)*S0 + lane], rlane(u, i+2), s2);
                s3 = fmaf(Mm[(i+3)*S0 + lane], rlane(u, i+3), s3);
            }
            v = 1.0f / ((s0+s1) + (s2+s3));
        }
        // final row softmax + expected position (u cancels)
        {
            float ss=0.f, sx=0.f, sy=0.f;
            #pragma unroll
            for (int j = 0; j < 64; ++j) {
                float pj = K[j] * rlane(v, j);
                ss += pj;
                sx = fmaf(pj, (float)(j & 7),  sx);
                sy = fmaf(pj, (float)(j >> 3), sy);
            }
            const float inv = 1.0f / ss;
            dispx[lane] = sx * inv - (float)(lane & 7);
            dispy[lane] = sy * inv - (float)(lane >> 3);
        }
    }
    __syncthreads();

    // ---- warp: bilinear border sample of z1 at (pos + 4*disp) ----
    #pragma unroll
    for (int rep = 0; rep < 4; ++rep) {
        const int p = rep * 256 + t;
        const int y = p >> 5, x = p & 31;
        const int m2 = (y >> 2) * 8 + (x >> 2);
        float gx = (float)(X0 + x) + 4.0f * dispx[m2];
        float gy = (float)(Y0 + y) + 4.0f * dispy[m2];
        gx = fminf(fmaxf(gx, 0.0f), 255.0f);
        gy = fminf(fmaxf(gy, 0.0f), 255.0f);
        const float x0f = floorf(gx), y0f = floorf(gy);
        const float wxf = gx - x0f, wyf = gy - y0f;
        const int xi0 = (int)x0f, yi0 = (int)y0f;
        const int xi1 = min(xi0 + 1, 255), yi1 = min(yi0 + 1, 255);
        const float w00 = (1.f-wxf)*(1.f-wyf), w01 = wxf*(1.f-wyf);
        const float w10 = (1.f-wxf)*wyf,       w11 = wxf*wyf;
        const float* basep = z1 + (size_t)(b * 4) * 65536;
        #pragma unroll
        for (int c = 0; c < 4; ++c) {
            const float* pc = basep + c * 65536;
            const float v00 = pc[yi0*256 + xi0], v01 = pc[yi0*256 + xi1];
            const float v10 = pc[yi1*256 + xi0], v11 = pc[yi1*256 + xi1];
            out[((size_t)(b*4+c)*256 + (Y0+y))*256 + X0 + x]
                = v00*w00 + v01*w01 + v10*w10 + v11*w11;
        }
    }
}

extern "C" void kernel_launch(void* const* d_in, const int* in_sizes, int n_in,
                              void* d_out, int out_size, void* d_ws, size_t ws_size,
                              hipStream_t stream) {
    (void)in_sizes; (void)n_in; (void)d_ws; (void)ws_size; (void)out_size;
    const float* z0 = (const float*)d_in[0];
    const float* z1 = (const float*)d_in[1];
    float* out = (float*)d_out;
    skw_kernel<<<dim3(1024), dim3(256), 0, stream>>>(z0, z1, out);
}